// Round 4
// baseline (7341.312 us; speedup 1.0000x reference)
//
#include <hip/hip_runtime.h>

#define BATCH 128
#define SEQ   1024
#define INSZ  128
#define HID   256
#define NBLK  32
#define NTHR  512
#define FPB   8            // features per block
#define EPSV  1e-5f

typedef __attribute__((ext_vector_type(4))) float f32x4;
typedef __attribute__((ext_vector_type(8))) short short8;
typedef unsigned long long u64;

__device__ __forceinline__ unsigned short f2bf(float f) {
  unsigned u = __builtin_bit_cast(unsigned, f);
  u += 0x7FFFu + ((u >> 16) & 1u);          // round-to-nearest-even
  return (unsigned short)(u >> 16);
}
__device__ __forceinline__ u64 cload64(const unsigned short* p) {
  return __hip_atomic_load((const u64*)p, __ATOMIC_RELAXED, __HIP_MEMORY_SCOPE_AGENT);
}
__device__ __forceinline__ void cstore64(unsigned short* p, u64 v) {
  __hip_atomic_store((u64*)p, v, __ATOMIC_RELAXED, __HIP_MEMORY_SCOPE_AGENT);
}

__launch_bounds__(NTHR, 2)
__global__ void bnlstm_kernel(const float* __restrict__ x,
                              const float* __restrict__ W,
                              const float* __restrict__ gamma,
                              const float* __restrict__ beta,
                              float* __restrict__ out,
                              unsigned short* __restrict__ hbuf,   // [2][128][256] bf16 row-major
                              unsigned* __restrict__ flags) {      // [8 wid][32 bid]
  __shared__ float red1[2][8][32];                 // parity-buffered BN partials
  __shared__ float red2[2][8][32];
  __shared__ float waveTr[8][16][17];              // per-wave gate transpose
  __shared__ unsigned short hpack[8][16][8];       // per-wave h row-pack (16B/row)

  const int tid   = threadIdx.x;
  const int bid   = blockIdx.x;
  const int lane  = tid & 63;
  const int wid   = tid >> 6;                      // wave w owns batch rows 16w..16w+15
  const int col16 = lane & 15;
  const int kg    = lane >> 4;
  const int d     = col16 & 3;
  const int q     = col16 >> 2;
  const int arow  = wid * 16 + col16;              // A-frag row (batch index)
  const int brow  = wid * 16 + kg * 4 + d;         // gate/output row (batch index)

  // ---- B fragments in registers: 32 cols = (j_local 0..7) x (gate 0..3) ----
  short8 wf[2][12];
  for (int cg = 0; cg < 2; ++cg) {
    const int c32 = cg * 16 + col16;
    const int wcol = (c32 & 3) * HID + bid * FPB + (c32 >> 2);
    for (int kt = 0; kt < 12; ++kt) {
      short8 v;
      for (int e = 0; e < 8; ++e)
        v[e] = (short)f2bf(W[(kt * 32 + kg * 8 + e) * 1024 + wcol]);
      wf[cg][kt] = v;
    }
  }
  float gam = 0.f, bet = 0.f;
  if (lane < 32) {
    gam = gamma[(lane & 3) * HID + bid * FPB + (lane >> 2)];
    bet = beta [(lane & 3) * HID + bid * FPB + (lane >> 2)];
  }
  // bias input skipped: BN subtracts the batch mean, cancelling it exactly.

  float cst[2] = {0.f, 0.f};
  float hnv[2];

  // x(t) A-frags, loaded one step ahead (plain cached loads)
  float4 xv[8];
  {
    const float* xr = x + (size_t)arow * (SEQ * INSZ) + kg * 8;
    #pragma unroll
    for (int kt = 0; kt < 4; ++kt) {
      xv[2 * kt]     = *(const float4*)(xr + kt * 32);
      xv[2 * kt + 1] = *(const float4*)(xr + kt * 32 + 4);
    }
  }

  for (int t = 0; t < SEQ; ++t) {
    const int pR = t & 1;
    f32x4 acc0 = {0.f, 0.f, 0.f, 0.f}, acc1 = {0.f, 0.f, 0.f, 0.f};

    // ---- x-part MFMAs first: independent of other blocks, overlaps their tail ----
    #pragma unroll
    for (int kt = 0; kt < 4; ++kt) {
      float4 f0 = xv[2 * kt], f1 = xv[2 * kt + 1];
      short8 ax;
      ax[0] = (short)f2bf(f0.x); ax[1] = (short)f2bf(f0.y);
      ax[2] = (short)f2bf(f0.z); ax[3] = (short)f2bf(f0.w);
      ax[4] = (short)f2bf(f1.x); ax[5] = (short)f2bf(f1.y);
      ax[6] = (short)f2bf(f1.z); ax[7] = (short)f2bf(f1.w);
      acc0 = __builtin_amdgcn_mfma_f32_16x16x32_bf16(ax, wf[0][kt], acc0, 0, 0, 0);
      acc1 = __builtin_amdgcn_mfma_f32_16x16x32_bf16(ax, wf[1][kt], acc1, 0, 0, 0);
    }

    if (t > 0) {
      // ---- poll only the 32 same-wid producer waves (they wrote our rows) ----
      const unsigned tv = (unsigned)t;
      while (true) {
        unsigned v = (lane < NBLK)
          ? __hip_atomic_load(&flags[wid * NBLK + lane], __ATOMIC_RELAXED,
                              __HIP_MEMORY_SCOPE_AGENT)
          : tv;
        if (__all((int)(v >= tv))) break;
      }
      // ---- h: IC -> registers directly as A-frags (no LDS, no barrier) ----
      const unsigned short* hb = hbuf + pR * (BATCH * HID) + arow * HID + kg * 8;
      u64 hv[16];
      #pragma unroll
      for (int kt = 0; kt < 8; ++kt) {
        hv[2 * kt]     = cload64(hb + kt * 32);
        hv[2 * kt + 1] = cload64(hb + kt * 32 + 4);
      }
      #pragma unroll
      for (int kt = 0; kt < 8; ++kt) {
        short8 af;
        *(u64*)&af       = hv[2 * kt];
        *((u64*)&af + 1) = hv[2 * kt + 1];
        acc0 = __builtin_amdgcn_mfma_f32_16x16x32_bf16(af, wf[0][4 + kt], acc0, 0, 0, 0);
        acc1 = __builtin_amdgcn_mfma_f32_16x16x32_bf16(af, wf[1][4 + kt], acc1, 0, 0, 0);
      }
    }

    // ---- BN partials (the ONLY intra-block barrier per step) ----
    {
      float a1 = acc0[0] + acc0[1] + acc0[2] + acc0[3];
      float b1 = acc0[0]*acc0[0] + acc0[1]*acc0[1] + acc0[2]*acc0[2] + acc0[3]*acc0[3];
      float a2 = acc1[0] + acc1[1] + acc1[2] + acc1[3];
      float b2 = acc1[0]*acc1[0] + acc1[1]*acc1[1] + acc1[2]*acc1[2] + acc1[3]*acc1[3];
      a1 += __shfl_xor(a1, 16); b1 += __shfl_xor(b1, 16);
      a1 += __shfl_xor(a1, 32); b1 += __shfl_xor(b1, 32);
      a2 += __shfl_xor(a2, 16); b2 += __shfl_xor(b2, 16);
      a2 += __shfl_xor(a2, 32); b2 += __shfl_xor(b2, 32);
      if (lane < 16) {
        red1[pR][wid][lane] = a1;       red2[pR][wid][lane] = b1;
        red1[pR][wid][16 + lane] = a2;  red2[pR][wid][16 + lane] = b2;
      }
    }
    __syncthreads();

    // ---- BN finalize: redundant per wave (no second barrier; red is parity-buffered) ----
    float sc0, sh0, sc1v, sh1v;
    {
      const int cidx = lane & 31;
      float S1 = 0.f, S2 = 0.f;
      #pragma unroll
      for (int w2 = 0; w2 < 8; ++w2) { S1 += red1[pR][w2][cidx]; S2 += red2[pR][w2][cidx]; }
      float mean = S1 * (1.f / BATCH);
      float var  = fmaxf(S2 * (1.f / BATCH) - mean * mean, 0.f);
      float scl = rsqrtf(var + EPSV) * gam;
      float shl = bet - mean * scl;
      sc0  = __shfl(scl, col16);       sh0  = __shfl(shl, col16);
      sc1v = __shfl(scl, 16 + col16);  sh1v = __shfl(shl, 16 + col16);
    }

    // ---- normalize + in-wave transpose + gates ----
    #pragma unroll
    for (int cg = 0; cg < 2; ++cg) {
      f32x4 a = cg ? acc1 : acc0;
      const float sc = cg ? sc1v : sc0, sh = cg ? sh1v : sh0;
      #pragma unroll
      for (int i = 0; i < 4; ++i)
        waveTr[wid][kg * 4 + i][col16] = a[i] * sc + sh;
      float g0 = waveTr[wid][kg * 4 + d][q * 4 + 0];
      float g1 = waveTr[wid][kg * 4 + d][q * 4 + 1];
      float g2 = waveTr[wid][kg * 4 + d][q * 4 + 2];
      float g3 = waveTr[wid][kg * 4 + d][q * 4 + 3];
      float ig = 1.f / (1.f + __expf(-g0));
      float fg = 1.f / (1.f + __expf(-g1));
      float gg = 1.f - 2.f / (__expf(2.f * g2) + 1.f);
      float og = 1.f / (1.f + __expf(-g3));
      float cn = fg * cst[cg] + ig * gg;
      float hn = og * (1.f - 2.f / (__expf(2.f * cn) + 1.f));
      cst[cg] = cn;
      hnv[cg] = hn;
      hpack[wid][kg * 4 + d][cg * 4 + q] = f2bf(hn);
    }

    // ---- publish h + per-wave flag: waits only THIS wave's 32 store acks ----
    if (t < SEQ - 1) {
      if (lane < 16) {
        const u64* hp = (const u64*)&hpack[wid][lane][0];
        u64 v0 = hp[0], v1 = hp[1];
        unsigned short* hd = hbuf + (pR ^ 1) * (BATCH * HID) + (wid * 16 + lane) * HID + bid * FPB;
        cstore64(hd, v0);
        cstore64(hd + 4, v1);
      }
      asm volatile("s_waitcnt vmcnt(0)" ::: "memory");   // h stores acked at IC
      if (lane == 0)
        __hip_atomic_store(&flags[wid * NBLK + bid], (unsigned)(t + 1),
                           __ATOMIC_RELAXED, __HIP_MEMORY_SCOPE_AGENT);
    }

    // ---- off-critical-path: out stores, tail, next-x loads (AFTER the flag) ----
    {
      float* po = &out[(size_t)brow * (SEQ * HID) + (size_t)t * HID + bid * FPB];
      po[q]     = hnv[0];
      po[4 + q] = hnv[1];
    }
    if (t == SEQ - 1) {
      float* ph = &out[(size_t)BATCH * SEQ * HID + (size_t)brow * HID + bid * FPB];
      ph[q] = hnv[0];                 ph[4 + q] = hnv[1];            // hy
      ph[BATCH * HID + q] = cst[0];   ph[BATCH * HID + 4 + q] = cst[1];  // cy
    } else {
      const float* xr = x + (size_t)arow * (SEQ * INSZ) + (size_t)(t + 1) * INSZ + kg * 8;
      #pragma unroll
      for (int kt = 0; kt < 4; ++kt) {
        xv[2 * kt]     = *(const float4*)(xr + kt * 32);
        xv[2 * kt + 1] = *(const float4*)(xr + kt * 32 + 4);
      }
    }
  }
}

extern "C" void kernel_launch(void* const* d_in, const int* in_sizes, int n_in,
                              void* d_out, int out_size, void* d_ws, size_t ws_size,
                              hipStream_t stream) {
  const float* x     = (const float*)d_in[0];
  const float* W     = (const float*)d_in[1];
  // d_in[2] = bias: cancelled by BatchNorm, unused.
  const float* gamma = (const float*)d_in[3];
  const float* beta  = (const float*)d_in[4];
  float* out = (float*)d_out;

  unsigned* flags = (unsigned*)d_ws;                               // 8x32 x 4B = 1 KB
  unsigned short* hbuf = (unsigned short*)((char*)d_ws + 4096);    // 2 x 64 KB

  // reset flags each call (t=0 skips h read, so hbuf needs no init)
  hipMemsetAsync(d_ws, 0, 4096, stream);
  hipLaunchKernelGGL(bnlstm_kernel, dim3(NBLK), dim3(NTHR), 0, stream,
                     x, W, gamma, beta, out, hbuf, flags);
}